// Round 15
// baseline (4792.307 us; speedup 1.0000x reference)
//
#include <hip/hip_runtime.h>
#include <cmath>

// GRU: B=32, T=512, E=512, H=1024, fp32.
// Phase 1: xgt[t][gate][j][b] = x @ w_ih^T (transposed store)
// Phase 2 (R14): R8's proven ring kernel (3.41ms) + PER-WAVE CHUNK GATE.
//   Wave w consumes only k-rows [64w,64w+64) = outputs of blocks
//   16w..16w+15 -> it polls exactly one 64B flag line and proceeds without
//   any gate barrier. Chunk h-regions are 8KB-aligned (no line sharing).
//   Two barriers/step remain: red_s handoff, and the tail-store drain
//   before the flag publish. Everything else identical to R8.

namespace {
constexpr int BATCH  = 32;
constexpr int TSTEPS = 512;
constexpr int EDIM   = 512;
constexpr int HDIM   = 1024;
constexpr int GDIM   = 3 * HDIM;
constexpr int SLOT   = HDIM * BATCH;          // 32768 floats = 128 KB

constexpr size_t XG_BYTES    = (size_t)TSTEPS * GDIM * BATCH * 4;  // 192 MiB
constexpr size_t FLAGS_BYTES = 4096;
constexpr size_t SLOT_BYTES  = (size_t)SLOT * 4;
}

// ---------------- Phase 1: xgt = x @ w_ih^T ----------------
__global__ __launch_bounds__(256)
void xg_gemm_f32(const float* __restrict__ x, const float* __restrict__ w_ih,
                 float* __restrict__ xgt)
{
    __shared__ float a_s[16 * 132];
    __shared__ float b_s[16 * 132];

    const int tid = threadIdx.x;
    const int n0 = blockIdx.x * 128;
    const int m0 = blockIdx.y * 128;
    const int tx = tid & 15;
    const int ty = tid >> 4;

    float acc[8][8];
    #pragma unroll
    for (int i = 0; i < 8; ++i)
        #pragma unroll
        for (int j = 0; j < 8; ++j) acc[i][j] = 0.f;

    const int r_ld = tid >> 2;
    const int kq4  = (tid & 3) * 4;

    for (int kc = 0; kc < EDIM; kc += 16) {
        __syncthreads();
        #pragma unroll
        for (int half = 0; half < 2; ++half) {
            const int r = r_ld + half * 64;
            const int m = m0 + r;
            const int bb = m & 31;
            const int tt = m >> 5;
            float4 av = *(const float4*)&x[((size_t)bb * TSTEPS + tt) * EDIM + kc + kq4];
            a_s[(kq4 + 0) * 132 + r] = av.x;
            a_s[(kq4 + 1) * 132 + r] = av.y;
            a_s[(kq4 + 2) * 132 + r] = av.z;
            a_s[(kq4 + 3) * 132 + r] = av.w;
            const int n = n0 + r;
            float4 bv = *(const float4*)&w_ih[(size_t)n * EDIM + kc + kq4];
            b_s[(kq4 + 0) * 132 + r] = bv.x;
            b_s[(kq4 + 1) * 132 + r] = bv.y;
            b_s[(kq4 + 2) * 132 + r] = bv.z;
            b_s[(kq4 + 3) * 132 + r] = bv.w;
        }
        __syncthreads();
        #pragma unroll
        for (int k = 0; k < 16; ++k) {
            float a_r[8], b_r[8];
            *(float4*)&a_r[0] = *(const float4*)&a_s[k * 132 + ty * 8];
            *(float4*)&a_r[4] = *(const float4*)&a_s[k * 132 + ty * 8 + 4];
            *(float4*)&b_r[0] = *(const float4*)&b_s[k * 132 + tx * 8];
            *(float4*)&b_r[4] = *(const float4*)&b_s[k * 132 + tx * 8 + 4];
            #pragma unroll
            for (int i = 0; i < 8; ++i)
                #pragma unroll
                for (int j = 0; j < 8; ++j)
                    acc[i][j] = fmaf(a_r[i], b_r[j], acc[i][j]);
        }
    }

    const int t  = (m0 >> 5) + (ty >> 2);
    const int b0 = (ty & 3) * 8;
    #pragma unroll
    for (int j = 0; j < 8; ++j) {
        const int g    = n0 + tx * 8 + j;
        const int gate = g >> 10;
        const int jj   = g & 1023;
        float* p = &xgt[(((size_t)t * 3 + gate) * 1024 + jj) * 32 + b0];
        *(float4*)p       = make_float4(acc[0][j], acc[1][j], acc[2][j], acc[3][j]);
        *(float4*)(p + 4) = make_float4(acc[4][j], acc[5][j], acc[6][j], acc[7][j]);
    }
}

// ---------------- Phase 2: ring + per-wave chunk gate ----------------
__global__ __launch_bounds__(1024, 4)
void gru_ring(const float* __restrict__ h0, const float* __restrict__ w_hh,
              const float* __restrict__ xgt, float* __restrict__ out,
              float* __restrict__ ring, unsigned* __restrict__ flags,
              int nslot)
{
    __shared__ float w_s[12 * 1032];       // 49.5 KB (+8 pad per row)
    __shared__ float red_s[16 * 8 * 83];   // 42.5 KB

    const int tid = threadIdx.x;
    const int bid = blockIdx.x;
    const int j0  = bid * 4;

    // w_s row = gate*4 + jl
    for (int i = tid; i < 12 * 256; i += 1024) {
        const int row  = i >> 8;
        const int c4   = (i & 255) * 4;
        const int gate = row >> 2;
        const int jl   = row & 3;
        *(float4*)&w_s[row * 1032 + c4] =
            *(const float4*)&w_hh[((size_t)gate * HDIM + j0 + jl) * HDIM + c4];
    }

    const int tjl = tid >> 5;   // tail j (tid<128)
    const int tb  = tid & 31;   // tail b

    float hp = 0.f, hnew = 0.f;
    if (tid < 128) {
        hp = h0[(size_t)tb * HDIM + j0 + tjl];
        __hip_atomic_store(&ring[(j0 + tjl) * 32 + tb], hp,
                           __ATOMIC_RELAXED, __HIP_MEMORY_SCOPE_AGENT);
    }

    // Entry: drain h0 stores, invalidate stale lines from prior replay, publish.
    __syncthreads();
    if (tid < 64) __builtin_amdgcn_fence(__ATOMIC_ACQUIRE, "agent");
    __syncthreads();
    if (tid == 0)
        __hip_atomic_store(&flags[bid], 1u,
                           __ATOMIC_RELAXED, __HIP_MEMORY_SCOPE_AGENT);

    // xg prefetch for t=0.
    float xr = 0.f, xz = 0.f, xn = 0.f;
    if (tid < 128) {
        const size_t base = (size_t)(j0 + tjl) * 32 + tb;
        xr = xgt[base];
        xz = xgt[base + 32768];
        xn = xgt[base + 65536];
    }

    const int wv   = tid >> 6;
    const int lane = tid & 63;
    const unsigned* const myflag = &flags[wv * 16 + (lane & 15)];  // one 64B line

    const int bgrp  = tid & 7;
    const int kseg  = tid >> 3;        // 0..127; wave w owns ksegs [8w,8w+8)
    const int b0    = bgrp * 4;
    const int kbase = kseg * 8;
    const int wvi   = tid >> 6;
    const int h3  = (tid >> 3) & 1;
    const int h4b = (tid >> 4) & 1;
    const int h5  = (tid >> 5) & 1;
    const int rbase = 6 * h3 + 3 * h4b;
    const int bb2   = 2 * h5;

    int slot = 0;
    int next_fence = nslot;

    for (int t = 0; t < TSTEPS; ++t) {
        const int slot_nx = (slot + 1 == nslot) ? 0 : slot + 1;

        // ---- per-wave chunk gate: only my 16 producers, one flag line ----
        {
            const unsigned tgt = (unsigned)(t + 1);
            for (;;) {
                unsigned f = __hip_atomic_load(myflag, __ATOMIC_RELAXED,
                                               __HIP_MEMORY_SCOPE_AGENT);
                if (__all(f >= tgt)) break;
                __builtin_amdgcn_s_sleep(1);
            }
        }
        if (t == next_fence) {   // ring-slot reuse boundary (rare)
            __builtin_amdgcn_fence(__ATOMIC_ACQUIRE, "agent");
            next_fence += nslot;
        }

        // h loads: normal cached float4; wave w's chunk is an 8KB-aligned
        // region written exactly by the blocks it gated on.
        const float* sp = ring + (size_t)slot * SLOT;
        float4 hv[8];
        #pragma unroll
        for (int i = 0; i < 8; ++i)
            hv[i] = *(const float4*)&sp[(kbase + i) * 32 + b0];

        float acc[12][4];
        #pragma unroll
        for (int r = 0; r < 12; ++r)
            #pragma unroll
            for (int b = 0; b < 4; ++b) acc[r][b] = 0.f;

        #pragma unroll
        for (int q = 0; q < 2; ++q)
            #pragma unroll
            for (int r = 0; r < 12; ++r) {
                const float4 w4 = *(const float4*)&w_s[r * 1032 + kbase + q * 4];
                const float wq[4] = {w4.x, w4.y, w4.z, w4.w};
                #pragma unroll
                for (int i = 0; i < 4; ++i) {
                    const float4 h4i = hv[q * 4 + i];
                    acc[r][0] = fmaf(wq[i], h4i.x, acc[r][0]);
                    acc[r][1] = fmaf(wq[i], h4i.y, acc[r][1]);
                    acc[r][2] = fmaf(wq[i], h4i.z, acc[r][2]);
                    acc[r][3] = fmaf(wq[i], h4i.w, acc[r][3]);
                }
            }

        // Scatter-reduce butterfly over in-wave ksegs (lane bits 3,4,5).
        float a6[6][4];
        #pragma unroll
        for (int m = 0; m < 6; ++m)
            #pragma unroll
            for (int b = 0; b < 4; ++b) {
                const float send = h3 ? acc[m][b] : acc[6 + m][b];
                const float recv = __shfl_xor(send, 8, 64);
                a6[m][b] = (h3 ? acc[6 + m][b] : acc[m][b]) + recv;
            }
        float a3[3][4];
        #pragma unroll
        for (int m = 0; m < 3; ++m)
            #pragma unroll
            for (int b = 0; b < 4; ++b) {
                const float send = h4b ? a6[m][b] : a6[3 + m][b];
                const float recv = __shfl_xor(send, 16, 64);
                a3[m][b] = (h4b ? a6[3 + m][b] : a6[m][b]) + recv;
            }
        float a2[3][2];
        #pragma unroll
        for (int m = 0; m < 3; ++m)
            #pragma unroll
            for (int b = 0; b < 2; ++b) {
                const float send = h5 ? a3[m][b] : a3[m][2 + b];
                const float recv = __shfl_xor(send, 32, 64);
                a2[m][b] = (h5 ? a3[m][2 + b] : a3[m][b]) + recv;
            }
        {
            float* dst = &red_s[(wvi * 8 + bgrp) * 83];
            #pragma unroll
            for (int m = 0; m < 3; ++m) {
                dst[(rbase + m) * 4 + bb2 + 0] = a2[m][0];
                dst[(rbase + m) * 4 + bb2 + 1] = a2[m][1];
            }
        }
        __syncthreads();   // barrier 1: red_s complete

        if (tid < 128) {
            const int bg = tb >> 2, bs = tb & 3;
            float s0 = 0.f, s1 = 0.f, s2 = 0.f;
            #pragma unroll
            for (int w = 0; w < 16; ++w) {
                const float* rs = &red_s[(w * 8 + bg) * 83 + bs];
                s0 += rs[(0 * 4 + tjl) * 4];
                s1 += rs[(1 * 4 + tjl) * 4];
                s2 += rs[(2 * 4 + tjl) * 4];
            }
            const float rg   = 1.f / (1.f + expf(-(xr + s0)));
            const float zg   = 1.f / (1.f + expf(-(xz + s1)));
            const float ng   = tanhf(xn + rg * s2);
            hnew = (1.f - zg) * ng + zg * hp;
            hp = hnew;
            if (t + 1 < TSTEPS)
                __hip_atomic_store(&ring[(size_t)slot_nx * SLOT + (j0 + tjl) * 32 + tb],
                                   hnew, __ATOMIC_RELAXED, __HIP_MEMORY_SCOPE_AGENT);
        }

        __syncthreads();   // barrier 2: tail ring-stores drained (vmcnt0)

        if (t + 1 < TSTEPS) {
            if (tid == 0)
                __hip_atomic_store(&flags[bid], (unsigned)(t + 2),
                                   __ATOMIC_RELAXED, __HIP_MEMORY_SCOPE_AGENT);
            // out store + next xg prefetch ride ahead of the next gate.
            if (tid < 128) {
                out[((size_t)tb * TSTEPS + t) * HDIM + j0 + tjl] = hnew;
                const size_t b2 = ((size_t)(t + 1) * 3072 + (j0 + tjl)) * 32 + tb;
                xr = xgt[b2];
                xz = xgt[b2 + 32768];
                xn = xgt[b2 + 65536];
            }
        } else {
            if (tid < 128)
                out[((size_t)tb * TSTEPS + t) * HDIM + j0 + tjl] = hnew;
        }

        slot = slot_nx;
    }
}

extern "C" void kernel_launch(void* const* d_in, const int* in_sizes, int n_in,
                              void* d_out, int out_size, void* d_ws, size_t ws_size,
                              hipStream_t stream)
{
    const float* x    = (const float*)d_in[0];
    const float* h0   = (const float*)d_in[1];
    const float* w_ih = (const float*)d_in[2];
    const float* w_hh = (const float*)d_in[3];
    float* out = (float*)d_out;

    char* ws = (char*)d_ws;
    float* xgt = (float*)ws;

    dim3 g1(GDIM / 128, (BATCH * TSTEPS) / 128);  // 24 x 128
    xg_gemm_f32<<<g1, 256, 0, stream>>>(x, w_ih, xgt);

    // Layout: [xgt 192MiB][flags 4KiB][ring nslot*128KiB]
    size_t avail = (ws_size > XG_BYTES + FLAGS_BYTES)
                       ? (ws_size - XG_BYTES - FLAGS_BYTES) : 0;
    int nslot = (int)(avail / SLOT_BYTES);
    if (nslot > TSTEPS) nslot = TSTEPS;
    if (nslot < 2) nslot = 2;

    unsigned* flags = (unsigned*)(ws + XG_BYTES);
    float* ring     = (float*)(ws + XG_BYTES + FLAGS_BYTES);
    hipMemsetAsync(flags, 0, FLAGS_BYTES, stream);
    gru_ring<<<256, 1024, 0, stream>>>(h0, w_hh, xgt, out, ring, flags, nslot);
}

// Round 16
// 3432.290 us; speedup vs baseline: 1.3962x; 1.3962x over previous
//
#include <hip/hip_runtime.h>
#include <cmath>

// GRU: B=32, T=512, E=512, H=1024, fp32.  (R15 = restore R8, best measured)
// Phase 1: xgt[t][gate][j][b] = x @ w_ih^T (transposed store)
// Phase 2: persistent ring kernel, 256 blocks x 1024 threads.
//   h state in an nslot-slot ring (128KB/slot). Producers write slots via
//   write-through agent atomics (-> L3). Consumers read with NORMAL cached
//   float4 loads: slot addresses reused only every nslot steps; one acquire
//   fence at entry + at the slot-reuse boundary. The 32 blocks of an XCD
//   share one L2 copy of h (~32x less L3 fan-out than L3-direct reads).
//   Barrier: packed 4B flags (256 = 16 lines); ONE wave per block polls
//   (4 flags/lane, __all on wave min) -- poll fan-out is the binding cost,
//   proven by R9/R14 regressions at 16x poll waves.
//   Step chain (measured floor ~6.5us): red_s barrier -> tail -> drain
//   barrier -> flag publish -> wave-poll -> barrier.

namespace {
constexpr int BATCH  = 32;
constexpr int TSTEPS = 512;
constexpr int EDIM   = 512;
constexpr int HDIM   = 1024;
constexpr int GDIM   = 3 * HDIM;
constexpr int SLOT   = HDIM * BATCH;          // 32768 floats = 128 KB

constexpr size_t XG_BYTES    = (size_t)TSTEPS * GDIM * BATCH * 4;  // 192 MiB
constexpr size_t FLAGS_BYTES = 4096;
constexpr size_t SLOT_BYTES  = (size_t)SLOT * 4;
}

// ---------------- Phase 1: xgt = x @ w_ih^T ----------------
__global__ __launch_bounds__(256)
void xg_gemm_f32(const float* __restrict__ x, const float* __restrict__ w_ih,
                 float* __restrict__ xgt)
{
    __shared__ float a_s[16 * 132];
    __shared__ float b_s[16 * 132];

    const int tid = threadIdx.x;
    const int n0 = blockIdx.x * 128;
    const int m0 = blockIdx.y * 128;
    const int tx = tid & 15;
    const int ty = tid >> 4;

    float acc[8][8];
    #pragma unroll
    for (int i = 0; i < 8; ++i)
        #pragma unroll
        for (int j = 0; j < 8; ++j) acc[i][j] = 0.f;

    const int r_ld = tid >> 2;
    const int kq4  = (tid & 3) * 4;

    for (int kc = 0; kc < EDIM; kc += 16) {
        __syncthreads();
        #pragma unroll
        for (int half = 0; half < 2; ++half) {
            const int r = r_ld + half * 64;
            const int m = m0 + r;
            const int bb = m & 31;
            const int tt = m >> 5;
            float4 av = *(const float4*)&x[((size_t)bb * TSTEPS + tt) * EDIM + kc + kq4];
            a_s[(kq4 + 0) * 132 + r] = av.x;
            a_s[(kq4 + 1) * 132 + r] = av.y;
            a_s[(kq4 + 2) * 132 + r] = av.z;
            a_s[(kq4 + 3) * 132 + r] = av.w;
            const int n = n0 + r;
            float4 bv = *(const float4*)&w_ih[(size_t)n * EDIM + kc + kq4];
            b_s[(kq4 + 0) * 132 + r] = bv.x;
            b_s[(kq4 + 1) * 132 + r] = bv.y;
            b_s[(kq4 + 2) * 132 + r] = bv.z;
            b_s[(kq4 + 3) * 132 + r] = bv.w;
        }
        __syncthreads();
        #pragma unroll
        for (int k = 0; k < 16; ++k) {
            float a_r[8], b_r[8];
            *(float4*)&a_r[0] = *(const float4*)&a_s[k * 132 + ty * 8];
            *(float4*)&a_r[4] = *(const float4*)&a_s[k * 132 + ty * 8 + 4];
            *(float4*)&b_r[0] = *(const float4*)&b_s[k * 132 + tx * 8];
            *(float4*)&b_r[4] = *(const float4*)&b_s[k * 132 + tx * 8 + 4];
            #pragma unroll
            for (int i = 0; i < 8; ++i)
                #pragma unroll
                for (int j = 0; j < 8; ++j)
                    acc[i][j] = fmaf(a_r[i], b_r[j], acc[i][j]);
        }
    }

    const int t  = (m0 >> 5) + (ty >> 2);
    const int b0 = (ty & 3) * 8;
    #pragma unroll
    for (int j = 0; j < 8; ++j) {
        const int g    = n0 + tx * 8 + j;
        const int gate = g >> 10;
        const int jj   = g & 1023;
        float* p = &xgt[(((size_t)t * 3 + gate) * 1024 + jj) * 32 + b0];
        *(float4*)p       = make_float4(acc[0][j], acc[1][j], acc[2][j], acc[3][j]);
        *(float4*)(p + 4) = make_float4(acc[4][j], acc[5][j], acc[6][j], acc[7][j]);
    }
}

// ---------------- Phase 2 (ring version, R8-proven) ----------------
__global__ __launch_bounds__(1024, 4)
void gru_ring(const float* __restrict__ h0, const float* __restrict__ w_hh,
              const float* __restrict__ xgt, float* __restrict__ out,
              float* __restrict__ ring, unsigned* __restrict__ flags,
              int nslot)
{
    __shared__ float w_s[12 * 1032];       // 49.5 KB (+8 pad per row)
    __shared__ float red_s[16 * 8 * 83];   // 42.5 KB

    const int tid = threadIdx.x;
    const int bid = blockIdx.x;
    const int j0  = bid * 4;

    for (int i = tid; i < 12 * 256; i += 1024) {
        const int row  = i >> 8;
        const int c4   = (i & 255) * 4;
        const int gate = row >> 2;
        const int jl   = row & 3;
        *(float4*)&w_s[row * 1032 + c4] =
            *(const float4*)&w_hh[((size_t)gate * HDIM + j0 + jl) * HDIM + c4];
    }

    const int tjl = tid >> 5;   // tail j (tid<128)
    const int tb  = tid & 31;   // tail b

    float hp = 0.f, hnew = 0.f;
    if (tid < 128) {
        hp = h0[(size_t)tb * HDIM + j0 + tjl];
        __hip_atomic_store(&ring[(j0 + tjl) * 32 + tb], hp,
                           __ATOMIC_RELAXED, __HIP_MEMORY_SCOPE_AGENT);
    }

    // Entry invalidate: drop any ring lines cached by a previous replay.
    __syncthreads();   // also drains h0 stores (vmcnt0 before s_barrier)
    if (tid < 64) __builtin_amdgcn_fence(__ATOMIC_ACQUIRE, "agent");
    __syncthreads();

    if (tid == 0)
        __hip_atomic_store(&flags[bid], 1u,
                           __ATOMIC_RELAXED, __HIP_MEMORY_SCOPE_AGENT);

    float xr = 0.f, xz = 0.f, xn = 0.f;
    if (tid < 128) {
        const size_t base = (size_t)(j0 + tjl) * 32 + tb;
        xr = xgt[base];
        xz = xgt[base + 32768];
        xn = xgt[base + 65536];
    }

    // wave-poll: 4 packed flags per lane, min across wave.
    if (tid < 64) {
        for (;;) {
            unsigned a0 = __hip_atomic_load(&flags[tid],       __ATOMIC_RELAXED, __HIP_MEMORY_SCOPE_AGENT);
            unsigned a1 = __hip_atomic_load(&flags[tid + 64],  __ATOMIC_RELAXED, __HIP_MEMORY_SCOPE_AGENT);
            unsigned a2 = __hip_atomic_load(&flags[tid + 128], __ATOMIC_RELAXED, __HIP_MEMORY_SCOPE_AGENT);
            unsigned a3 = __hip_atomic_load(&flags[tid + 192], __ATOMIC_RELAXED, __HIP_MEMORY_SCOPE_AGENT);
            unsigned m01 = a0 < a1 ? a0 : a1;
            unsigned m23 = a2 < a3 ? a2 : a3;
            unsigned mn  = m01 < m23 ? m01 : m23;
            if (__all(mn >= 1u)) break;
            __builtin_amdgcn_s_sleep(1);
        }
    }
    __syncthreads();

    const int bgrp  = tid & 7;
    const int kseg  = tid >> 3;        // 0..127
    const int b0    = bgrp * 4;
    const int kbase = kseg * 8;
    const int wvi   = tid >> 6;
    const int h3  = (tid >> 3) & 1;
    const int h4b = (tid >> 4) & 1;
    const int h5  = (tid >> 5) & 1;
    const int rbase = 6 * h3 + 3 * h4b;
    const int bb2   = 2 * h5;

    int slot = 0;                 // t % nslot
    int next_fence = nslot;       // fence when entering step == multiple of nslot

    for (int t = 0; t < TSTEPS; ++t) {
        const float* sp = ring + (size_t)slot * SLOT;
        const int slot_nx = (slot + 1 == nslot) ? 0 : slot + 1;

        // h loads: NORMAL cached float4 (fresh addresses -> L2-shared per XCD).
        float4 hv[8];
        #pragma unroll
        for (int i = 0; i < 8; ++i)
            hv[i] = *(const float4*)&sp[(kbase + i) * 32 + b0];

        float acc[12][4];
        #pragma unroll
        for (int r = 0; r < 12; ++r)
            #pragma unroll
            for (int b = 0; b < 4; ++b) acc[r][b] = 0.f;

        #pragma unroll
        for (int q = 0; q < 2; ++q)
            #pragma unroll
            for (int r = 0; r < 12; ++r) {
                const float4 w4 = *(const float4*)&w_s[r * 1032 + kbase + q * 4];
                const float wq[4] = {w4.x, w4.y, w4.z, w4.w};
                #pragma unroll
                for (int i = 0; i < 4; ++i) {
                    const float4 h4i = hv[q * 4 + i];
                    acc[r][0] = fmaf(wq[i], h4i.x, acc[r][0]);
                    acc[r][1] = fmaf(wq[i], h4i.y, acc[r][1]);
                    acc[r][2] = fmaf(wq[i], h4i.z, acc[r][2]);
                    acc[r][3] = fmaf(wq[i], h4i.w, acc[r][3]);
                }
            }

        // Scatter-reduce butterfly over in-wave ksegs (lane bits 3,4,5).
        float a6[6][4];
        #pragma unroll
        for (int m = 0; m < 6; ++m)
            #pragma unroll
            for (int b = 0; b < 4; ++b) {
                const float send = h3 ? acc[m][b] : acc[6 + m][b];
                const float recv = __shfl_xor(send, 8, 64);
                a6[m][b] = (h3 ? acc[6 + m][b] : acc[m][b]) + recv;
            }
        float a3[3][4];
        #pragma unroll
        for (int m = 0; m < 3; ++m)
            #pragma unroll
            for (int b = 0; b < 4; ++b) {
                const float send = h4b ? a6[m][b] : a6[3 + m][b];
                const float recv = __shfl_xor(send, 16, 64);
                a3[m][b] = (h4b ? a6[3 + m][b] : a6[m][b]) + recv;
            }
        float a2[3][2];
        #pragma unroll
        for (int m = 0; m < 3; ++m)
            #pragma unroll
            for (int b = 0; b < 2; ++b) {
                const float send = h5 ? a3[m][b] : a3[m][2 + b];
                const float recv = __shfl_xor(send, 32, 64);
                a2[m][b] = (h5 ? a3[m][2 + b] : a3[m][b]) + recv;
            }
        {
            float* dst = &red_s[(wvi * 8 + bgrp) * 83];
            #pragma unroll
            for (int m = 0; m < 3; ++m) {
                dst[(rbase + m) * 4 + bb2 + 0] = a2[m][0];
                dst[(rbase + m) * 4 + bb2 + 1] = a2[m][1];
            }
        }
        __syncthreads();

        if (tid < 128) {
            const int bg = tb >> 2, bs = tb & 3;
            float s0 = 0.f, s1 = 0.f, s2 = 0.f;
            #pragma unroll
            for (int w = 0; w < 16; ++w) {
                const float* rs = &red_s[(w * 8 + bg) * 83 + bs];
                s0 += rs[(0 * 4 + tjl) * 4];
                s1 += rs[(1 * 4 + tjl) * 4];
                s2 += rs[(2 * 4 + tjl) * 4];
            }
            const float rg   = 1.f / (1.f + expf(-(xr + s0)));
            const float zg   = 1.f / (1.f + expf(-(xz + s1)));
            const float ng   = tanhf(xn + rg * s2);
            hnew = (1.f - zg) * ng + zg * hp;
            hp = hnew;
            if (t + 1 < TSTEPS)
                __hip_atomic_store(&ring[(size_t)slot_nx * SLOT + (j0 + tjl) * 32 + tb],
                                   hnew, __ATOMIC_RELAXED, __HIP_MEMORY_SCOPE_AGENT);
        }

        // barrier drains tail h-stores (vmcnt0) before the flag store.
        __syncthreads();

        if (t + 1 < TSTEPS) {
            if (tid == 0)
                __hip_atomic_store(&flags[bid], (unsigned)(t + 2),
                                   __ATOMIC_RELAXED, __HIP_MEMORY_SCOPE_AGENT);

            // out store + next xg prefetch ride the wait.
            if (tid < 128) {
                out[((size_t)tb * TSTEPS + t) * HDIM + j0 + tjl] = hnew;
                const size_t b2 = ((size_t)(t + 1) * 3072 + (j0 + tjl)) * 32 + tb;
                xr = xgt[b2];
                xz = xgt[b2 + 32768];
                xn = xgt[b2 + 65536];
            }

            if (tid < 64) {
                const unsigned tgt = (unsigned)(t + 2);
                for (;;) {
                    unsigned a0 = __hip_atomic_load(&flags[tid],       __ATOMIC_RELAXED, __HIP_MEMORY_SCOPE_AGENT);
                    unsigned a1 = __hip_atomic_load(&flags[tid + 64],  __ATOMIC_RELAXED, __HIP_MEMORY_SCOPE_AGENT);
                    unsigned a2 = __hip_atomic_load(&flags[tid + 128], __ATOMIC_RELAXED, __HIP_MEMORY_SCOPE_AGENT);
                    unsigned a3 = __hip_atomic_load(&flags[tid + 192], __ATOMIC_RELAXED, __HIP_MEMORY_SCOPE_AGENT);
                    unsigned m01 = a0 < a1 ? a0 : a1;
                    unsigned m23 = a2 < a3 ? a2 : a3;
                    unsigned mn  = m01 < m23 ? m01 : m23;
                    if (__all(mn >= tgt)) break;
                    __builtin_amdgcn_s_sleep(1);
                }
            }
            __syncthreads();

            // Slot-reuse fence: entering step (t+1) == multiple of nslot.
            if (t + 1 == next_fence) {
                if (tid < 64) __builtin_amdgcn_fence(__ATOMIC_ACQUIRE, "agent");
                __syncthreads();
                next_fence += nslot;
            }
        } else {
            if (tid < 128)
                out[((size_t)tb * TSTEPS + t) * HDIM + j0 + tjl] = hnew;
        }

        slot = slot_nx;
    }
}

extern "C" void kernel_launch(void* const* d_in, const int* in_sizes, int n_in,
                              void* d_out, int out_size, void* d_ws, size_t ws_size,
                              hipStream_t stream)
{
    const float* x    = (const float*)d_in[0];
    const float* h0   = (const float*)d_in[1];
    const float* w_ih = (const float*)d_in[2];
    const float* w_hh = (const float*)d_in[3];
    float* out = (float*)d_out;

    char* ws = (char*)d_ws;
    float* xgt = (float*)ws;

    dim3 g1(GDIM / 128, (BATCH * TSTEPS) / 128);  // 24 x 128
    xg_gemm_f32<<<g1, 256, 0, stream>>>(x, w_ih, xgt);

    // Layout: [xgt 192MiB][flags 4KiB][ring nslot*128KiB]
    size_t avail = (ws_size > XG_BYTES + FLAGS_BYTES)
                       ? (ws_size - XG_BYTES - FLAGS_BYTES) : 0;
    int nslot = (int)(avail / SLOT_BYTES);
    if (nslot > TSTEPS) nslot = TSTEPS;
    if (nslot < 2) nslot = 2;

    unsigned* flags = (unsigned*)(ws + XG_BYTES);
    float* ring     = (float*)(ws + XG_BYTES + FLAGS_BYTES);
    hipMemsetAsync(flags, 0, FLAGS_BYTES, stream);
    gru_ring<<<256, 1024, 0, stream>>>(h0, w_hh, xgt, out, ring, flags, nslot);
}